// Round 7
// baseline (81.244 us; speedup 1.0000x reference)
//
#include <hip/hip_runtime.h>

#define NUM_INPUTS 4096
#define NUM_LEAVES 2048
#define BLK 1024

// out[b, l] = x[b, idx[l]]
// Direct gather, no LDS: one 1024-thread block per row, 2 outputs/thread.
// Row reuse (each 64B line touched ~8x) is served by L1: only 2 blocks/CU
// (thread-limited) -> 2 rows = 32 KiB hot per CU = L1 capacity. Zero
// barriers, zero staging instructions; writes coalesced float2.
__global__ __launch_bounds__(BLK) void FrozenInputToLeaf_direct(
    const float* __restrict__ x,
    const int* __restrict__ idx,
    float* __restrict__ out) {
    const int t = threadIdx.x;
    const size_t b = blockIdx.x;

    // idx: 8 KiB, L2-hot across all 16384 blocks. int2 per thread, coalesced.
    const int2 i2 = ((const int2*)idx)[t];

    const float* __restrict__ row = x + b * NUM_INPUTS;

    float2 v;
    v.x = row[i2.x];
    v.y = row[i2.y];

    float2* __restrict__ ov = (float2*)(out + b * NUM_LEAVES);
    ov[t] = v;
}

extern "C" void kernel_launch(void* const* d_in, const int* in_sizes, int n_in,
                              void* d_out, int out_size, void* d_ws, size_t ws_size,
                              hipStream_t stream) {
    const float* x = (const float*)d_in[0];
    const int* idx = (const int*)d_in[1];
    float* out = (float*)d_out;

    const int batch = in_sizes[0] / NUM_INPUTS;  // 16384

    FrozenInputToLeaf_direct<<<batch, BLK, 0, stream>>>(x, idx, out);
}